// Round 1
// baseline (5038.296 us; speedup 1.0000x reference)
//
#include <hip/hip_runtime.h>
#include <math.h>

#define N_NODES 50000
#define E_EDGES 800000
#define ET (E_EDGES + N_NODES)
#define IN_DIM 3000
#define HID 512
#define LAT 30
#define XH_STRIDE 32
#define NEG_SLOPE 0.2f

__device__ __forceinline__ float eluf(float x) { return x > 0.f ? x : expm1f(x); }

// order-preserving float->uint key for atomicMax-based segment max
__device__ __forceinline__ unsigned fkey(float f) {
    unsigned u = __float_as_uint(f);
    return (u & 0x80000000u) ? ~u : (u | 0x80000000u);
}
__device__ __forceinline__ float funkey(unsigned k) {
    unsigned u = (k & 0x80000000u) ? (k ^ 0x80000000u) : ~k;
    return __uint_as_float(u);
}

__device__ __forceinline__ float4 load4_guard(const float* __restrict__ p, int n_valid) {
    float4 v = make_float4(0.f, 0.f, 0.f, 0.f);
    if (n_valid >= 4) {
        v = *(const float4*)p;
    } else {
        if (n_valid > 0) v.x = p[0];
        if (n_valid > 1) v.y = p[1];
        if (n_valid > 2) v.z = p[2];
    }
    return v;
}

__global__ void k_init(float* __restrict__ zbuf, unsigned* __restrict__ amax, float* __restrict__ denom) {
    int gid = blockIdx.x * 256 + threadIdx.x;
    if (gid < N_NODES * XH_STRIDE) zbuf[gid] = 0.f;
    if (gid < N_NODES) { amax[gid] = 0u; denom[gid] = 0.f; }
}

__global__ void k_transpose_w(const float* __restrict__ w, float* __restrict__ wt) {
    int idx = blockIdx.x * 256 + threadIdx.x;
    if (idx < HID * LAT) {
        int j = idx / LAT, c = idx % LAT;
        wt[c * HID + j] = w[idx];
    }
}

// C[i,col] = act( sum_k A[i,k]*B(k,col) + bias[col] )
// B_KMAJOR: B(k,col) at B[col*ldb + k]  (encoder: enc_w1[j,k])
// else:     B(k,col) at B[k*ldb + col] (decoder: enc_w1[j,c])
template<bool B_KMAJOR, bool DO_ELU>
__global__ __launch_bounds__(256, 2)
void k_gemm(const float* __restrict__ A, const float* __restrict__ B,
            const float* __restrict__ bias, float* __restrict__ C,
            int M, int Ncols, int K, int lda, int ldb, int ldc) {
    const int BM = 64, BN = 128, BK = 32;
    __shared__ float As[BK][68];
    __shared__ float Bs[BK][132];
    int tid = threadIdx.x;
    int tx = tid & 15, ty = tid >> 4;
    int i0 = blockIdx.x * BM;
    int c0 = blockIdx.y * BN;

    float acc[4][8];
#pragma unroll
    for (int q = 0; q < 4; ++q)
#pragma unroll
        for (int p = 0; p < 8; ++p) acc[q][p] = 0.f;

    for (int kt = 0; kt < K; kt += BK) {
        // A tile: 64 rows x 32 k = 512 float4, 2 per thread
#pragma unroll
        for (int s = 0; s < 2; ++s) {
            int idx = tid + s * 256;
            int r = idx >> 3, kk = (idx & 7) * 4;
            int row = i0 + r, k = kt + kk;
            float4 v = make_float4(0.f, 0.f, 0.f, 0.f);
            if (row < M && k < K) v = load4_guard(A + (size_t)row * lda + k, K - k);
            As[kk + 0][r] = v.x; As[kk + 1][r] = v.y; As[kk + 2][r] = v.z; As[kk + 3][r] = v.w;
        }
        // B tile: 32 k x 128 cols = 1024 float4, 4 per thread
        if (B_KMAJOR) {
#pragma unroll
            for (int s = 0; s < 4; ++s) {
                int idx = tid + s * 256;
                int r = idx >> 3, kk = (idx & 7) * 4;
                int col = c0 + r, k = kt + kk;
                float4 v = make_float4(0.f, 0.f, 0.f, 0.f);
                if (col < Ncols && k < K) v = load4_guard(B + (size_t)col * ldb + k, K - k);
                Bs[kk + 0][r] = v.x; Bs[kk + 1][r] = v.y; Bs[kk + 2][r] = v.z; Bs[kk + 3][r] = v.w;
            }
        } else {
#pragma unroll
            for (int s = 0; s < 4; ++s) {
                int idx = tid + s * 256;
                int kk = idx >> 5, c4 = (idx & 31) * 4;
                int k = kt + kk, col = c0 + c4;
                float4 v = make_float4(0.f, 0.f, 0.f, 0.f);
                if (k < K && col < Ncols) v = load4_guard(B + (size_t)k * ldb + col, Ncols - col);
                *(float4*)&Bs[kk][c4] = v;
            }
        }
        __syncthreads();
#pragma unroll
        for (int kk = 0; kk < BK; ++kk) {
            float4 a  = *(const float4*)&As[kk][ty * 4];
            float4 bl = *(const float4*)&Bs[kk][tx * 4];
            float4 bh = *(const float4*)&Bs[kk][64 + tx * 4];
            float av[4] = {a.x, a.y, a.z, a.w};
            float bv[8] = {bl.x, bl.y, bl.z, bl.w, bh.x, bh.y, bh.z, bh.w};
#pragma unroll
            for (int q = 0; q < 4; ++q)
#pragma unroll
                for (int p = 0; p < 8; ++p)
                    acc[q][p] = fmaf(av[q], bv[p], acc[q][p]);
        }
        __syncthreads();
    }

#pragma unroll
    for (int q = 0; q < 4; ++q) {
        int row = i0 + ty * 4 + q;
        if (row >= M) continue;
#pragma unroll
        for (int half = 0; half < 2; ++half) {
            int cb = c0 + half * 64 + tx * 4;
#pragma unroll
            for (int p = 0; p < 4; ++p) {
                int col = cb + p;
                if (col < Ncols) {
                    float v = acc[q][half * 4 + p] + bias[col];
                    if (DO_ELU) v = eluf(v);
                    C[(size_t)row * ldc + col] = v;
                }
            }
        }
    }
}

// xh = h @ gat_w ; si[n] = dot(att_i, xh[n]) ; sj[n] = dot(att_j, xh[n])
__global__ __launch_bounds__(256)
void k_gat_proj(const float* __restrict__ h, const float* __restrict__ gat_w,
                const float* __restrict__ gat_att,
                float* __restrict__ xh, float* __restrict__ si, float* __restrict__ sj) {
    __shared__ float gwl[HID * LAT];
    __shared__ float atl[2 * LAT];
    int tid = threadIdx.x;
    for (int i = tid; i < HID * LAT; i += 256) gwl[i] = gat_w[i];
    if (tid < 2 * LAT) atl[tid] = gat_att[tid];
    __syncthreads();
    int n = blockIdx.x * 8 + (tid >> 5);
    int c = tid & 31;
    if (n >= N_NODES) return;
    bool act = c < LAT;
    float accv = 0.f;
    const float4* h4 = (const float4*)(h + (size_t)n * HID);
#pragma unroll 4
    for (int j4 = 0; j4 < HID / 4; ++j4) {
        float4 hv = h4[j4];
        if (act) {
            int b = j4 * 4 * LAT + c;
            accv = fmaf(hv.x, gwl[b], accv);
            accv = fmaf(hv.y, gwl[b + LAT], accv);
            accv = fmaf(hv.z, gwl[b + 2 * LAT], accv);
            accv = fmaf(hv.w, gwl[b + 3 * LAT], accv);
        }
    }
    float xhv = act ? accv : 0.f;
    xh[(size_t)n * XH_STRIDE + c] = xhv;
    float sip = act ? atl[c] * xhv : 0.f;
    float sjp = act ? atl[LAT + c] * xhv : 0.f;
#pragma unroll
    for (int off = 16; off > 0; off >>= 1) {
        sip += __shfl_down(sip, off, 32);
        sjp += __shfl_down(sjp, off, 32);
    }
    if (c == 0) { si[n] = sip; sj[n] = sjp; }
}

__global__ void k_edge_alpha(const int* __restrict__ ei, const float* __restrict__ eattr,
                             const float* __restrict__ si, const float* __restrict__ sj,
                             float* __restrict__ alphaE, unsigned* __restrict__ amax) {
    int e = blockIdx.x * 256 + threadIdx.x;
    if (e >= ET) return;
    int s, d; float w;
    if (e < E_EDGES) { s = ei[e]; d = ei[E_EDGES + e]; w = eattr[e]; }
    else { s = d = e - E_EDGES; w = 1.f; }
    float a = si[d] + sj[s];
    a = a >= 0.f ? a : NEG_SLOPE * a;
    a *= w;
    alphaE[e] = a;
    atomicMax(&amax[d], fkey(a));
}

__global__ void k_edge_exp(const int* __restrict__ ei, float* __restrict__ alphaE,
                           const unsigned* __restrict__ amax, float* __restrict__ denom) {
    int e = blockIdx.x * 256 + threadIdx.x;
    if (e >= ET) return;
    int d = (e < E_EDGES) ? ei[E_EDGES + e] : (e - E_EDGES);
    float m = funkey(amax[d]);
    float v = expf(alphaE[e] - m);
    alphaE[e] = v;
    atomicAdd(&denom[d], v);
}

__global__ void k_edge_scatter(const int* __restrict__ ei, const float* __restrict__ xh,
                               const float* __restrict__ alphaE, const float* __restrict__ denom,
                               float* __restrict__ zbuf) {
    int gid = blockIdx.x * 256 + threadIdx.x;
    int e = gid >> 5, c = gid & 31;
    if (e >= ET || c >= LAT) return;
    int s, d;
    if (e < E_EDGES) { s = ei[e]; d = ei[E_EDGES + e]; }
    else { s = d = e - E_EDGES; }
    float w = alphaE[e] / (denom[d] + 1e-16f);
    atomicAdd(&zbuf[(size_t)d * XH_STRIDE + c], xh[(size_t)s * XH_STRIDE + c] * w);
}

__global__ void k_z(const float* __restrict__ gat_b, float* __restrict__ zbuf, float* __restrict__ zout) {
    int gid = blockIdx.x * 256 + threadIdx.x;
    int n = gid >> 5, c = gid & 31;
    if (n >= N_NODES) return;
    if (c < LAT) {
        float v = eluf(zbuf[gid] + gat_b[c]);
        zbuf[gid] = v;
        zout[(size_t)n * LAT + c] = v;
    }
}

// hd[i,j] = elu( sum_c z[i,c]*dec_w1[j,c] + dec_b1[j] ), via transposed WT[c,j]
__global__ __launch_bounds__(256)
void k_dec1(const float* __restrict__ zbuf, const float* __restrict__ wt,
            const float* __restrict__ b, float* __restrict__ hd) {
    int gid = blockIdx.x * 256 + threadIdx.x;
    if (gid >= N_NODES * HID) return;
    int j = gid & (HID - 1);
    size_t i = (size_t)(gid >> 9);
    float acc = b[j];
#pragma unroll
    for (int c = 0; c < LAT; ++c)
        acc = fmaf(zbuf[i * XH_STRIDE + c], wt[c * HID + j], acc);
    hd[gid] = eluf(acc);
}

extern "C" void kernel_launch(void* const* d_in, const int* in_sizes, int n_in,
                              void* d_out, int out_size, void* d_ws, size_t ws_size,
                              hipStream_t stream) {
    const float* x      = (const float*)d_in[0];
    const int*   ei     = (const int*)d_in[1];
    const float* eattr  = (const float*)d_in[2];
    const float* enc_w1 = (const float*)d_in[3];
    const float* enc_b1 = (const float*)d_in[4];
    const float* gat_w  = (const float*)d_in[5];
    const float* gat_att= (const float*)d_in[6];
    const float* gat_b  = (const float*)d_in[7];
    const float* dec_w1 = (const float*)d_in[8];
    const float* dec_b1 = (const float*)d_in[9];
    const float* dec_b2 = (const float*)d_in[10];

    float* out  = (float*)d_out;
    float* xrec = out;                                   // 50000*3000
    float* zout = out + (size_t)N_NODES * IN_DIM;        // 50000*30

    float* ws = (float*)d_ws;
    float*    h      = ws;                    // 25,600,000 floats (reused as hd)
    float*    xh     = ws + 25600000;         //  1,600,000
    float*    zbuf   = ws + 27200000;         //  1,600,000
    float*    si     = ws + 28800000;         //     50,000
    float*    sj     = ws + 28850000;         //     50,000
    unsigned* amax   = (unsigned*)(ws + 28900000); // 50,000
    float*    denom  = ws + 28950000;         //     50,000
    float*    alphaE = ws + 29000000;         //    850,000
    float*    wt     = ws + 29850000;         //     15,360

    (void)in_sizes; (void)n_in; (void)out_size; (void)ws_size;

    k_init<<<(N_NODES * XH_STRIDE + 255) / 256, 256, 0, stream>>>(zbuf, amax, denom);
    k_transpose_w<<<(HID * LAT + 255) / 256, 256, 0, stream>>>(dec_w1, wt);

    // h = elu(x @ enc_w1^T + enc_b1)
    {
        dim3 g((N_NODES + 63) / 64, (HID + 127) / 128);
        k_gemm<true, true><<<g, 256, 0, stream>>>(x, enc_w1, enc_b1, h,
                                                  N_NODES, HID, IN_DIM, IN_DIM, IN_DIM, HID);
    }
    k_gat_proj<<<(N_NODES + 7) / 8, 256, 0, stream>>>(h, gat_w, gat_att, xh, si, sj);
    k_edge_alpha<<<(ET + 255) / 256, 256, 0, stream>>>(ei, eattr, si, sj, alphaE, amax);
    k_edge_exp<<<(ET + 255) / 256, 256, 0, stream>>>(ei, alphaE, amax, denom);
    k_edge_scatter<<<((size_t)ET * 32 + 255) / 256, 256, 0, stream>>>(ei, xh, alphaE, denom, zbuf);
    k_z<<<(N_NODES * 32 + 255) / 256, 256, 0, stream>>>(gat_b, zbuf, zout);
    k_dec1<<<(N_NODES * HID + 255) / 256, 256, 0, stream>>>(zbuf, wt, dec_b1, h /*hd*/);

    // x_recon = hd @ enc_w1 + dec_b2
    {
        dim3 g((N_NODES + 63) / 64, (IN_DIM + 127) / 128);
        k_gemm<false, false><<<g, 256, 0, stream>>>(h, enc_w1, dec_b2, xrec,
                                                    N_NODES, IN_DIM, HID, HID, IN_DIM, IN_DIM);
    }
}

// Round 2
// 1741.435 us; speedup vs baseline: 2.8932x; 2.8932x over previous
//
#include <hip/hip_runtime.h>
#include <hip/hip_bf16.h>
#include <math.h>

#define N_NODES 50000
#define E_EDGES 800000
#define ET (E_EDGES + N_NODES)
#define IN_DIM 3000
#define HID 512
#define LAT 30
#define XH_STRIDE 32
#define NEG_SLOPE 0.2f
#define KPAD 3072

typedef __bf16 bfv8 __attribute__((ext_vector_type(8)));
typedef float f32x4 __attribute__((ext_vector_type(4)));

__device__ __forceinline__ float eluf(float x) { return x > 0.f ? x : expm1f(x); }

__device__ __forceinline__ unsigned fkey(float f) {
    unsigned u = __float_as_uint(f);
    return (u & 0x80000000u) ? ~u : (u | 0x80000000u);
}
__device__ __forceinline__ float funkey(unsigned k) {
    unsigned u = (k & 0x80000000u) ? (k ^ 0x80000000u) : ~k;
    return __uint_as_float(u);
}

__global__ void k_init(float* __restrict__ zbuf, unsigned* __restrict__ amax, float* __restrict__ denom) {
    int gid = blockIdx.x * 256 + threadIdx.x;
    if (gid < N_NODES * XH_STRIDE) zbuf[gid] = 0.f;
    if (gid < N_NODES) { amax[gid] = 0u; denom[gid] = 0.f; }
}

__global__ void k_transpose_w(const float* __restrict__ w, float* __restrict__ wt) {
    int idx = blockIdx.x * 256 + threadIdx.x;
    if (idx < HID * LAT) {
        int j = idx / LAT, c = idx % LAT;
        wt[c * HID + j] = w[idx];
    }
}

// enc_w1 [512][3000] f32 -> w1b [512][3072] bf16 (K-padded) and w1bt [3072][512] bf16 (transposed, N-padded)
__global__ void k_conv_w(const float* __restrict__ w, __bf16* __restrict__ w1b, __bf16* __restrict__ w1bt) {
    int idx = blockIdx.x * 256 + threadIdx.x;
    if (idx >= HID * KPAD) return;
    int j = idx / KPAD, k = idx - j * KPAD;
    float v = (k < IN_DIM) ? w[(size_t)j * IN_DIM + k] : 0.f;
    __bf16 b = (__bf16)v;
    w1b[(size_t)j * KPAD + k] = b;
    w1bt[(size_t)k * HID + j] = b;
}

// C[row,col] = act( sum_k A[row,k] * B(k,col) + bias[col] )
// A: f32 row-major [M][lda], reg-staged with on-the-fly bf16 conversion (guards row<M, k<Kreal).
// Bb: bf16 "B^T" layout [Ncols_pad][ldb] (row = output col, contiguous K), pre-padded with zeros.
template<bool DO_ELU>
__global__ __launch_bounds__(256, 2)
void k_gemm_mfma(const float* __restrict__ A, const __bf16* __restrict__ Bb,
                 const float* __restrict__ bias, float* __restrict__ C,
                 int M, int Nreal, int Kreal, int lda, int ldb, int ldc) {
    __shared__ __bf16 As[128 * 32];
    __shared__ __bf16 Bs[128 * 32];
    const int tid = threadIdx.x;
    const int lane = tid & 63, wv = tid >> 6;
    const int wr = wv >> 1, wc = wv & 1;
    const int l16 = lane & 15, lh = lane >> 4;
    const int i0 = blockIdx.y * 128;
    const int c0 = blockIdx.x * 128;

    f32x4 acc[4][4] = {};

    for (int kt = 0; kt < Kreal; kt += 32) {
        // ---- B tile: 128 cols x 32 k bf16 = 8 KB via global_load_lds (16B/lane) ----
#pragma unroll
        for (int s = 0; s < 2; ++s) {
            int cb = wv * 2 + s;                 // 1KB chunk id (0..7)
            int c = cb * 64 + lane;              // 16B chunk idx (0..511)
            int col = c >> 2, kc = c & 3;
            const __bf16* g = Bb + (size_t)(c0 + col) * ldb + kt + kc * 8;
            __builtin_amdgcn_global_load_lds(
                (const __attribute__((address_space(1))) void*)g,
                (__attribute__((address_space(3))) void*)(Bs + (size_t)cb * 512),
                16, 0, 0);
        }
        // ---- A tile: 128 rows x 32 k, f32 -> bf16 reg-staged ----
#pragma unroll
        for (int s = 0; s < 2; ++s) {
            int c = tid + s * 256;               // 0..511
            int row = c >> 2, kc = c & 3;
            int grow = i0 + row, gk = kt + kc * 8;
            float4 v0 = make_float4(0.f, 0.f, 0.f, 0.f);
            float4 v1 = make_float4(0.f, 0.f, 0.f, 0.f);
            if (grow < M && gk < Kreal) {        // Kreal % 8 == 0: chunk fully valid or fully OOB
                const float4* p = (const float4*)(A + (size_t)grow * lda + gk);
                v0 = p[0]; v1 = p[1];
            }
            bfv8 pk;
            pk[0] = (__bf16)v0.x; pk[1] = (__bf16)v0.y; pk[2] = (__bf16)v0.z; pk[3] = (__bf16)v0.w;
            pk[4] = (__bf16)v1.x; pk[5] = (__bf16)v1.y; pk[6] = (__bf16)v1.z; pk[7] = (__bf16)v1.w;
            *(bfv8*)(As + (size_t)c * 8) = pk;
        }
        __syncthreads();

        bfv8 af[4], bfr[4];
#pragma unroll
        for (int mi = 0; mi < 4; ++mi)
            af[mi] = *(const bfv8*)(As + (size_t)(wr * 64 + mi * 16 + l16) * 32 + lh * 8);
#pragma unroll
        for (int ni = 0; ni < 4; ++ni)
            bfr[ni] = *(const bfv8*)(Bs + (size_t)(wc * 64 + ni * 16 + l16) * 32 + lh * 8);
#pragma unroll
        for (int mi = 0; mi < 4; ++mi)
#pragma unroll
            for (int ni = 0; ni < 4; ++ni)
                acc[mi][ni] = __builtin_amdgcn_mfma_f32_16x16x32_bf16(af[mi], bfr[ni], acc[mi][ni], 0, 0, 0);
        __syncthreads();
    }

    // epilogue: C/D layout col = lane&15, row = (lane>>4)*4 + reg  [m89-verified]
#pragma unroll
    for (int ni = 0; ni < 4; ++ni) {
        int col = c0 + wc * 64 + ni * 16 + l16;
        if (col >= Nreal) continue;
        float bv = bias[col];
#pragma unroll
        for (int mi = 0; mi < 4; ++mi) {
            int row0 = i0 + wr * 64 + mi * 16 + lh * 4;
#pragma unroll
            for (int r = 0; r < 4; ++r) {
                int row = row0 + r;
                if (row < M) {
                    float v = acc[mi][ni][r] + bv;
                    if (DO_ELU) v = eluf(v);
                    C[(size_t)row * ldc + col] = v;
                }
            }
        }
    }
}

// xh = h @ gat_w ; si[n] = dot(att_i, xh[n]) ; sj[n] = dot(att_j, xh[n])
__global__ __launch_bounds__(256)
void k_gat_proj(const float* __restrict__ h, const float* __restrict__ gat_w,
                const float* __restrict__ gat_att,
                float* __restrict__ xh, float* __restrict__ si, float* __restrict__ sj) {
    __shared__ float gwl[HID * LAT];
    __shared__ float atl[2 * LAT];
    int tid = threadIdx.x;
    for (int i = tid; i < HID * LAT; i += 256) gwl[i] = gat_w[i];
    if (tid < 2 * LAT) atl[tid] = gat_att[tid];
    __syncthreads();
    int n = blockIdx.x * 8 + (tid >> 5);
    int c = tid & 31;
    if (n >= N_NODES) return;
    bool act = c < LAT;
    float accv = 0.f;
    const float4* h4 = (const float4*)(h + (size_t)n * HID);
#pragma unroll 4
    for (int j4 = 0; j4 < HID / 4; ++j4) {
        float4 hv = h4[j4];
        if (act) {
            int b = j4 * 4 * LAT + c;
            accv = fmaf(hv.x, gwl[b], accv);
            accv = fmaf(hv.y, gwl[b + LAT], accv);
            accv = fmaf(hv.z, gwl[b + 2 * LAT], accv);
            accv = fmaf(hv.w, gwl[b + 3 * LAT], accv);
        }
    }
    float xhv = act ? accv : 0.f;
    xh[(size_t)n * XH_STRIDE + c] = xhv;
    float sip = act ? atl[c] * xhv : 0.f;
    float sjp = act ? atl[LAT + c] * xhv : 0.f;
#pragma unroll
    for (int off = 16; off > 0; off >>= 1) {
        sip += __shfl_down(sip, off, 32);
        sjp += __shfl_down(sjp, off, 32);
    }
    if (c == 0) { si[n] = sip; sj[n] = sjp; }
}

__global__ void k_edge_alpha(const int* __restrict__ ei, const float* __restrict__ eattr,
                             const float* __restrict__ si, const float* __restrict__ sj,
                             float* __restrict__ alphaE, unsigned* __restrict__ amax) {
    int e = blockIdx.x * 256 + threadIdx.x;
    if (e >= ET) return;
    int s, d; float w;
    if (e < E_EDGES) { s = ei[e]; d = ei[E_EDGES + e]; w = eattr[e]; }
    else { s = d = e - E_EDGES; w = 1.f; }
    float a = si[d] + sj[s];
    a = a >= 0.f ? a : NEG_SLOPE * a;
    a *= w;
    alphaE[e] = a;
    atomicMax(&amax[d], fkey(a));
}

__global__ void k_edge_exp(const int* __restrict__ ei, float* __restrict__ alphaE,
                           const unsigned* __restrict__ amax, float* __restrict__ denom) {
    int e = blockIdx.x * 256 + threadIdx.x;
    if (e >= ET) return;
    int d = (e < E_EDGES) ? ei[E_EDGES + e] : (e - E_EDGES);
    float m = funkey(amax[d]);
    float v = expf(alphaE[e] - m);
    alphaE[e] = v;
    atomicAdd(&denom[d], v);
}

__global__ void k_edge_scatter(const int* __restrict__ ei, const float* __restrict__ xh,
                               const float* __restrict__ alphaE, const float* __restrict__ denom,
                               float* __restrict__ zbuf) {
    int gid = blockIdx.x * 256 + threadIdx.x;
    int e = gid >> 5, c = gid & 31;
    if (e >= ET || c >= LAT) return;
    int s, d;
    if (e < E_EDGES) { s = ei[e]; d = ei[E_EDGES + e]; }
    else { s = d = e - E_EDGES; }
    float w = alphaE[e] / (denom[d] + 1e-16f);
    atomicAdd(&zbuf[(size_t)d * XH_STRIDE + c], xh[(size_t)s * XH_STRIDE + c] * w);
}

__global__ void k_z(const float* __restrict__ gat_b, float* __restrict__ zbuf, float* __restrict__ zout) {
    int gid = blockIdx.x * 256 + threadIdx.x;
    int n = gid >> 5, c = gid & 31;
    if (n >= N_NODES) return;
    if (c < LAT) {
        float v = eluf(zbuf[gid] + gat_b[c]);
        zbuf[gid] = v;
        zout[(size_t)n * LAT + c] = v;
    }
}

// hd[i,j] = elu( sum_c z[i,c]*dec_w1[j,c] + dec_b1[j] ), via transposed WT[c,j]
__global__ __launch_bounds__(256)
void k_dec1(const float* __restrict__ zbuf, const float* __restrict__ wt,
            const float* __restrict__ b, float* __restrict__ hd) {
    int gid = blockIdx.x * 256 + threadIdx.x;
    if (gid >= N_NODES * HID) return;
    int j = gid & (HID - 1);
    size_t i = (size_t)(gid >> 9);
    float acc = b[j];
#pragma unroll
    for (int c = 0; c < LAT; ++c)
        acc = fmaf(zbuf[i * XH_STRIDE + c], wt[c * HID + j], acc);
    hd[gid] = eluf(acc);
}

extern "C" void kernel_launch(void* const* d_in, const int* in_sizes, int n_in,
                              void* d_out, int out_size, void* d_ws, size_t ws_size,
                              hipStream_t stream) {
    const float* x      = (const float*)d_in[0];
    const int*   ei     = (const int*)d_in[1];
    const float* eattr  = (const float*)d_in[2];
    const float* enc_w1 = (const float*)d_in[3];
    const float* enc_b1 = (const float*)d_in[4];
    const float* gat_w  = (const float*)d_in[5];
    const float* gat_att= (const float*)d_in[6];
    const float* gat_b  = (const float*)d_in[7];
    const float* dec_w1 = (const float*)d_in[8];
    const float* dec_b1 = (const float*)d_in[9];
    const float* dec_b2 = (const float*)d_in[10];

    float* out  = (float*)d_out;
    float* xrec = out;                                   // 50000*3000
    float* zout = out + (size_t)N_NODES * IN_DIM;        // 50000*30

    float* ws = (float*)d_ws;
    float*    h      = ws;                         // 25,600,000 floats (h, then hd)
    float*    xh     = ws + 25600000;              //  1,600,000
    float*    zbuf   = ws + 27200000;              //  1,600,000
    float*    si     = ws + 28800000;              //     50,000
    float*    sj     = ws + 28850000;              //     50,000
    unsigned* amax   = (unsigned*)(ws + 28900000); //     50,000
    float*    denom  = ws + 28950000;              //     50,000
    float*    alphaE = ws + 29000000;              //    850,000
    float*    wt     = ws + 29850000;              //     15,360
    __bf16*   w1b    = (__bf16*)(ws + 29865360);   // 512*3072 bf16 = 786,432 floats
    __bf16*   w1bt   = (__bf16*)(ws + 30651792);   // 3072*512 bf16 = 786,432 floats

    (void)in_sizes; (void)n_in; (void)out_size; (void)ws_size;

    k_init<<<(N_NODES * XH_STRIDE + 255) / 256, 256, 0, stream>>>(zbuf, amax, denom);
    k_transpose_w<<<(HID * LAT + 255) / 256, 256, 0, stream>>>(dec_w1, wt);
    k_conv_w<<<(HID * KPAD + 255) / 256, 256, 0, stream>>>(enc_w1, w1b, w1bt);

    // h = elu(x @ enc_w1^T + enc_b1):  A=x [50000][3000] f32, B^T = w1b [512][3072] bf16
    {
        dim3 g(HID / 128, (N_NODES + 127) / 128);
        k_gemm_mfma<true><<<g, 256, 0, stream>>>(x, w1b, enc_b1, h,
                                                 N_NODES, HID, IN_DIM, IN_DIM, KPAD, HID);
    }
    k_gat_proj<<<(N_NODES + 7) / 8, 256, 0, stream>>>(h, gat_w, gat_att, xh, si, sj);
    k_edge_alpha<<<(ET + 255) / 256, 256, 0, stream>>>(ei, eattr, si, sj, alphaE, amax);
    k_edge_exp<<<(ET + 255) / 256, 256, 0, stream>>>(ei, alphaE, amax, denom);
    k_edge_scatter<<<((size_t)ET * 32 + 255) / 256, 256, 0, stream>>>(ei, xh, alphaE, denom, zbuf);
    k_z<<<(N_NODES * 32 + 255) / 256, 256, 0, stream>>>(gat_b, zbuf, zout);
    k_dec1<<<(N_NODES * HID + 255) / 256, 256, 0, stream>>>(zbuf, wt, dec_b1, h /*hd*/);

    // x_recon = hd @ enc_w1 + dec_b2:  A=hd [50000][512] f32, B^T = w1bt [3072][512] bf16
    {
        dim3 g(KPAD / 128, (N_NODES + 127) / 128);
        k_gemm_mfma<false><<<g, 256, 0, stream>>>(h, w1bt, dec_b2, xrec,
                                                  N_NODES, IN_DIM, HID, HID, HID, IN_DIM);
    }
}